// Round 1
// baseline (642.409 us; speedup 1.0000x reference)
//
#include <hip/hip_runtime.h>
#include <math.h>

// Uniform extended grid: grid[t] = (t-3)*0.4 - 1, t = 0..11  (12 knots)
#define GRIDV(t) ((float)((t) - 3) * 0.4f - 1.0f)

__device__ __forceinline__ float silu_f(float x) {
    return x / (1.0f + expf(-x));
}

// Cox-de-Boor, degree 3, 8 final bases (matches reference b_splines exactly)
__device__ __forceinline__ void bspline8(float x, float* __restrict__ b) {
    float t[11];
#pragma unroll
    for (int i = 0; i < 11; ++i)
        t[i] = (x >= GRIDV(i) && x < GRIDV(i + 1)) ? 1.0f : 0.0f;
#pragma unroll
    for (int k = 1; k <= 3; ++k) {
#pragma unroll
        for (int i = 0; i < 11 - k; ++i) {
            float gl  = GRIDV(i);
            float gkl = GRIDV(i + k);
            float g1  = GRIDV(i + 1);
            float gr  = GRIDV(i + k + 1);
            t[i] = (x - gl) / (gkl - gl) * t[i] + (gr - x) / (gr - g1) * t[i + 1];
        }
    }
#pragma unroll
    for (int i = 0; i < 8; ++i) b[i] = t[i];
}

// ---------------------------------------------------------------------------
// Kernel 1: feature transform.  H[b][side*128+o] = sum_k A[b][k]*W[o][k] + bias[o]
// A = stm (side 0) / nstm (side 1), 32768x768.  W = ft_w 128x768.
// grid (512, 2), block 256.  Tile: 64 rows x 128 cols, BK=32.
// ---------------------------------------------------------------------------
#define FT_BM 64
#define FT_BK 32

__global__ __launch_bounds__(256) void ft_gemm_kernel(
        const float* __restrict__ stm, const float* __restrict__ nstm,
        const float* __restrict__ W, const float* __restrict__ bias,
        float* __restrict__ H) {
    const int side = blockIdx.y;
    const float* __restrict__ A = (side == 0) ? stm : nstm;
    const int r0 = blockIdx.x * FT_BM;
    const int t = threadIdx.x;

    __shared__ float As[FT_BK][FT_BM];   // [k][row]
    __shared__ float Ws[FT_BK][128];     // [k][col]

    const int tx = t % 32;   // cols tx*4 .. tx*4+3
    const int ty = t / 32;   // rows ty*8 .. ty*8+7

    float acc[8][4];
#pragma unroll
    for (int i = 0; i < 8; ++i)
#pragma unroll
        for (int j = 0; j < 4; ++j) acc[i][j] = 0.f;

    for (int k0 = 0; k0 < 768; k0 += FT_BK) {
        // stage A tile: 64 rows x 32 k; thread loads 8 consecutive k of one row
        {
            const int row = t / 4;
            const int kg = (t % 4) * 8;
            const float4* src = reinterpret_cast<const float4*>(
                &A[(size_t)(r0 + row) * 768 + k0 + kg]);
            float4 v0 = src[0];
            float4 v1 = src[1];
            As[kg + 0][row] = v0.x; As[kg + 1][row] = v0.y;
            As[kg + 2][row] = v0.z; As[kg + 3][row] = v0.w;
            As[kg + 4][row] = v1.x; As[kg + 5][row] = v1.y;
            As[kg + 6][row] = v1.z; As[kg + 7][row] = v1.w;
        }
        // stage W tile: 128 cols x 32 k; thread loads 16 consecutive k of one col
        {
            const int col = t / 2;
            const int kg = (t % 2) * 16;
            const float4* src = reinterpret_cast<const float4*>(
                &W[(size_t)col * 768 + k0 + kg]);
#pragma unroll
            for (int q = 0; q < 4; ++q) {
                float4 v = src[q];
                Ws[kg + q * 4 + 0][col] = v.x;
                Ws[kg + q * 4 + 1][col] = v.y;
                Ws[kg + q * 4 + 2][col] = v.z;
                Ws[kg + q * 4 + 3][col] = v.w;
            }
        }
        __syncthreads();
#pragma unroll
        for (int kk = 0; kk < FT_BK; ++kk) {
            const float4* ap = reinterpret_cast<const float4*>(&As[kk][ty * 8]);
            float4 a0 = ap[0], a1 = ap[1];
            float4 bv = *reinterpret_cast<const float4*>(&Ws[kk][tx * 4]);
            float a[8] = {a0.x, a0.y, a0.z, a0.w, a1.x, a1.y, a1.z, a1.w};
            float b[4] = {bv.x, bv.y, bv.z, bv.w};
#pragma unroll
            for (int i = 0; i < 8; ++i)
#pragma unroll
                for (int j = 0; j < 4; ++j) acc[i][j] += a[i] * b[j];
        }
        __syncthreads();
    }

    float4 bv = *reinterpret_cast<const float4*>(&bias[tx * 4]);
#pragma unroll
    for (int i = 0; i < 8; ++i) {
        const int r = r0 + ty * 8 + i;
        float4 o4;
        o4.x = acc[i][0] + bv.x; o4.y = acc[i][1] + bv.y;
        o4.z = acc[i][2] + bv.z; o4.w = acc[i][3] + bv.w;
        *reinterpret_cast<float4*>(&H[(size_t)r * 256 + side * 128 + tx * 4]) = o4;
    }
}

// ---------------------------------------------------------------------------
// Kernel 2: KAN layer 1.  x = H (32768x256) ->
//   H2[b][o] = sum_j ( silu(x[b][j])*bw[o][j] + sum_v bases_v(x[b][j])*sw[o][j][v] )
// Treated as GEMM with expanded A (K = 256*9) computed on the fly into LDS.
// grid (512), block 256.  Tile: 64 rows x 128 cols, 8 features (=72 k) per step.
// ---------------------------------------------------------------------------
#define K1_BM 64
#define K1_JB 8
#define K1_BK (K1_JB * 9)   // 72

__global__ __launch_bounds__(256) void kan1_kernel(
        const float* __restrict__ H,    // 32768 x 256
        const float* __restrict__ bw,   // 128 x 256
        const float* __restrict__ sw,   // 128 x 256 x 8
        float* __restrict__ H2) {       // 32768 x 128
    const int r0 = blockIdx.x * K1_BM;
    const int t = threadIdx.x;

    __shared__ float phiT[K1_BK][K1_BM];   // 72 x 64  (18 KB)
    __shared__ float WsT[K1_BK][128];      // 72 x 128 (36 KB)

    const int tx = t % 32;
    const int ty = t / 32;

    float acc[8][4];
#pragma unroll
    for (int i = 0; i < 8; ++i)
#pragma unroll
        for (int j = 0; j < 4; ++j) acc[i][j] = 0.f;

    for (int jb = 0; jb < 256; jb += K1_JB) {
        // phi staging: 512 (row, f) pairs, 2 per thread
#pragma unroll
        for (int q = 0; q < 2; ++q) {
            const int p = t + q * 256;
            const int row = p % K1_BM;
            const int f = p / K1_BM;    // 0..7
            const float x = H[(size_t)(r0 + row) * 256 + jb + f];
            float bas[8];
            bspline8(x, bas);
            phiT[f * 9 + 0][row] = silu_f(x);
#pragma unroll
            for (int v = 0; v < 8; ++v) phiT[f * 9 + 1 + v][row] = bas[v];
        }
        // weight staging: 1024 (col, f) pairs, 4 per thread
#pragma unroll
        for (int q = 0; q < 4; ++q) {
            const int p = t + q * 256;
            const int col = p % 128;
            const int f = p / 128;      // 0..7
            WsT[f * 9 + 0][col] = bw[(size_t)col * 256 + jb + f];
            const float4* sp = reinterpret_cast<const float4*>(
                &sw[((size_t)col * 256 + jb + f) * 8]);
            float4 s0 = sp[0], s1 = sp[1];
            WsT[f * 9 + 1][col] = s0.x; WsT[f * 9 + 2][col] = s0.y;
            WsT[f * 9 + 3][col] = s0.z; WsT[f * 9 + 4][col] = s0.w;
            WsT[f * 9 + 5][col] = s1.x; WsT[f * 9 + 6][col] = s1.y;
            WsT[f * 9 + 7][col] = s1.z; WsT[f * 9 + 8][col] = s1.w;
        }
        __syncthreads();
#pragma unroll 4
        for (int kk = 0; kk < K1_BK; ++kk) {
            const float4* ap = reinterpret_cast<const float4*>(&phiT[kk][ty * 8]);
            float4 a0 = ap[0], a1 = ap[1];
            float4 bv = *reinterpret_cast<const float4*>(&WsT[kk][tx * 4]);
            float a[8] = {a0.x, a0.y, a0.z, a0.w, a1.x, a1.y, a1.z, a1.w};
            float b[4] = {bv.x, bv.y, bv.z, bv.w};
#pragma unroll
            for (int i = 0; i < 8; ++i)
#pragma unroll
                for (int j = 0; j < 4; ++j) acc[i][j] += a[i] * b[j];
        }
        __syncthreads();
    }

#pragma unroll
    for (int i = 0; i < 8; ++i) {
        const int r = r0 + ty * 8 + i;
        float4 o4;
        o4.x = acc[i][0]; o4.y = acc[i][1]; o4.z = acc[i][2]; o4.w = acc[i][3];
        *reinterpret_cast<float4*>(&H2[(size_t)r * 128 + tx * 4]) = o4;
    }
}

// ---------------------------------------------------------------------------
// Kernel 3: KAN layer 2 + sigmoid.  One wave per output row.
// grid (8192), block 256 (4 waves).
// ---------------------------------------------------------------------------
__global__ __launch_bounds__(256) void kan2_kernel(
        const float* __restrict__ H2,   // 32768 x 128
        const float* __restrict__ w2b,  // 128
        const float* __restrict__ w2s,  // 128 x 8
        float* __restrict__ out) {      // 32768
    const int wave = threadIdx.x / 64;
    const int lane = threadIdx.x % 64;
    const int row = blockIdx.x * 4 + wave;

    float sum = 0.f;
#pragma unroll
    for (int half = 0; half < 2; ++half) {
        const int j = lane + half * 64;
        const float x = H2[(size_t)row * 128 + j];
        float bas[8];
        bspline8(x, bas);
        float s = silu_f(x) * w2b[j];
#pragma unroll
        for (int v = 0; v < 8; ++v) s += bas[v] * w2s[j * 8 + v];
        sum += s;
    }
#pragma unroll
    for (int off = 32; off > 0; off >>= 1)
        sum += __shfl_down(sum, off, 64);
    if (lane == 0) out[row] = 1.0f / (1.0f + expf(-sum));
}

// ---------------------------------------------------------------------------
extern "C" void kernel_launch(void* const* d_in, const int* in_sizes, int n_in,
                              void* d_out, int out_size, void* d_ws, size_t ws_size,
                              hipStream_t stream) {
    const float* stm  = (const float*)d_in[0];
    const float* nstm = (const float*)d_in[1];
    const float* ft_w = (const float*)d_in[2];
    const float* ft_b = (const float*)d_in[3];
    const float* k1bw = (const float*)d_in[4];
    const float* k1sw = (const float*)d_in[5];
    const float* k2bw = (const float*)d_in[6];
    const float* k2sw = (const float*)d_in[7];
    float* out = (float*)d_out;

    float* H  = (float*)d_ws;                         // 32768*256 f32 (33.6 MB)
    float* H2 = H + (size_t)32768 * 256;              // 32768*128 f32 (16.8 MB)

    ft_gemm_kernel<<<dim3(512, 2), 256, 0, stream>>>(stm, nstm, ft_w, ft_b, H);
    kan1_kernel<<<dim3(512), 256, 0, stream>>>(H, k1bw, k1sw, H2);
    kan2_kernel<<<dim3(8192), 256, 0, stream>>>(H2, k2bw, k2sw, out);
}

// Round 2
// 137.709 us; speedup vs baseline: 4.6650x; 4.6650x over previous
//
#include <hip/hip_runtime.h>
#include <math.h>
#include <stdint.h>

typedef __attribute__((ext_vector_type(8))) short bf16x8;
typedef __attribute__((ext_vector_type(4))) float f32x4;

__device__ __forceinline__ unsigned short f2bf(float f) {
    union { float f; uint32_t u; } c; c.f = f;
    uint32_t u = c.u;
    u += 0x7FFFu + ((u >> 16) & 1u);
    return (unsigned short)(u >> 16);
}
__device__ __forceinline__ uint32_t pack2(float a, float b) {
    return (uint32_t)f2bf(a) | ((uint32_t)f2bf(b) << 16);
}
__device__ __forceinline__ float bf2f(unsigned short h) {
    union { uint32_t u; float f; } c; c.u = ((uint32_t)h) << 16;
    return c.f;
}
__device__ __forceinline__ float silu_f(float x) {
    return x / (1.0f + __expf(-x));
}

// Uniform cardinal cubic B-spline bases on grid g_i = -2.2 + 0.4*i.
// b[v] = N3((x+2.2)/0.4 - v), N3(s) = (max(2-|s-2|,0)^3 - 4*max(1-|s-2|,0)^3)/6.
// Mathematically identical to the reference Cox-de-Boor recursion (uniform knots).
__device__ __forceinline__ void bspline8(float x, float* __restrict__ b) {
    const float tt = (x + 2.2f) * 2.5f;
#pragma unroll
    for (int v = 0; v < 8; ++v) {
        float y = fabsf(tt - (float)(v + 2));
        float p = fmaxf(2.0f - y, 0.0f);
        float q = fmaxf(1.0f - y, 0.0f);
        b[v] = (p * p * p - 4.0f * q * q * q) * (1.0f / 6.0f);
    }
}

// ---------------------------------------------------------------------------
// prep kernels: fp32 weights -> bf16 (and KAN1 weights padded to K=16/feature)
// ---------------------------------------------------------------------------
__global__ __launch_bounds__(256) void prep_ftw(const float* __restrict__ ftw,
                                                unsigned short* __restrict__ Wb) {
    const int idx = blockIdx.x * 256 + threadIdx.x;   // 98304 = 128*768
    Wb[idx] = f2bf(ftw[idx]);
}

__global__ __launch_bounds__(256) void prep_bp(const float* __restrict__ bw,
                                               const float* __restrict__ sw,
                                               unsigned short* __restrict__ Bp) {
    const int idx = blockIdx.x * 256 + threadIdx.x;   // 524288 = 128*4096
    const int n = idx >> 12;
    const int k = idx & 4095;
    const int f = k >> 4;
    const int v = k & 15;
    float val = 0.f;
    if (v == 0) val = bw[n * 256 + f];
    else if (v <= 8) val = sw[(size_t)(n * 256 + f) * 8 + (v - 1)];
    Bp[idx] = f2bf(val);
}

// ---------------------------------------------------------------------------
// FT GEMM (bf16 MFMA): H[b][side*128+o] = A[b][:] . ft_w[o][:] + bias[o]
// BM=128, BN=128 (full), BK=64.  grid (256, 2), block 256 (4 waves, 2x2 of 64x64)
// ---------------------------------------------------------------------------
__global__ __launch_bounds__(256) void ft_mfma(
        const float* __restrict__ stm, const float* __restrict__ nstm,
        const unsigned short* __restrict__ Wb, const float* __restrict__ bias,
        float* __restrict__ H) {
    __shared__ char lds[32768];          // As 16 KB | Bs 16 KB
    char* smA = lds;
    char* smB = lds + 16384;
    const int side = blockIdx.y;
    const float* __restrict__ A = side ? nstm : stm;
    const int r0 = blockIdx.x * 128;
    const int t = threadIdx.x;
    const int lane = t & 63, wid = t >> 6;
    const int wr = wid >> 1, wc = wid & 1;
    const int fr = lane & 15;
    const int fkb = (lane >> 4) * 8;

    const int arow = t >> 1;             // 0..127
    const int akh = (t & 1) * 32;        // 0 / 32

    f32x4 zero4 = {0.f, 0.f, 0.f, 0.f};
    f32x4 acc[4][4];
#pragma unroll
    for (int mt = 0; mt < 4; ++mt)
#pragma unroll
        for (int nt = 0; nt < 4; ++nt) acc[mt][nt] = zero4;

    for (int k0 = 0; k0 < 768; k0 += 64) {
        // stage A (fp32 -> bf16): 32 floats/thread
        const float4* ap = reinterpret_cast<const float4*>(
            &A[(size_t)(r0 + arow) * 768 + k0 + akh]);
#pragma unroll
        for (int q = 0; q < 4; ++q) {
            float4 u = ap[2 * q], v = ap[2 * q + 1];
            int4 w;
            w.x = (int)pack2(u.x, u.y); w.y = (int)pack2(u.z, u.w);
            w.z = (int)pack2(v.x, v.y); w.w = (int)pack2(v.z, v.w);
            uint32_t off = (uint32_t)arow * 128u + (uint32_t)(akh + q * 8) * 2u;
            off ^= (uint32_t)(arow & 7) << 4;
            *reinterpret_cast<int4*>(smA + off) = w;
        }
        // stage B (already bf16): 64 B/thread
        const int4* bp = reinterpret_cast<const int4*>(
            &Wb[(size_t)arow * 768 + k0 + akh]);
#pragma unroll
        for (int q = 0; q < 4; ++q) {
            int4 w = bp[q];
            uint32_t off = (uint32_t)arow * 128u + (uint32_t)(akh + q * 8) * 2u;
            off ^= (uint32_t)(arow & 7) << 4;
            *reinterpret_cast<int4*>(smB + off) = w;
        }
        __syncthreads();
#pragma unroll
        for (int ks = 0; ks < 2; ++ks) {
            const int kb = ks * 32 + fkb;
            bf16x8 a[4], b[4];
#pragma unroll
            for (int mt = 0; mt < 4; ++mt) {
                uint32_t row = (uint32_t)(wr * 64 + mt * 16 + fr);
                uint32_t off = (row * 128u + (uint32_t)kb * 2u) ^ ((row & 7u) << 4);
                a[mt] = *reinterpret_cast<const bf16x8*>(smA + off);
            }
#pragma unroll
            for (int nt = 0; nt < 4; ++nt) {
                uint32_t row = (uint32_t)(wc * 64 + nt * 16 + fr);
                uint32_t off = (row * 128u + (uint32_t)kb * 2u) ^ ((row & 7u) << 4);
                b[nt] = *reinterpret_cast<const bf16x8*>(smB + off);
            }
#pragma unroll
            for (int mt = 0; mt < 4; ++mt)
#pragma unroll
                for (int nt = 0; nt < 4; ++nt)
                    acc[mt][nt] = __builtin_amdgcn_mfma_f32_16x16x32_bf16(
                        a[mt], b[nt], acc[mt][nt], 0, 0, 0);
        }
        __syncthreads();
    }
    // epilogue: C/D layout col=lane&15, row=(lane>>4)*4+j  (m89)
#pragma unroll
    for (int nt = 0; nt < 4; ++nt) {
        const int col = wc * 64 + nt * 16 + fr;
        const float bv = bias[col];
#pragma unroll
        for (int mt = 0; mt < 4; ++mt)
#pragma unroll
            for (int j = 0; j < 4; ++j) {
                const int row = r0 + wr * 64 + mt * 16 + (lane >> 4) * 4 + j;
                H[(size_t)row * 256 + side * 128 + col] = acc[mt][nt][j] + bv;
            }
    }
}

// ---------------------------------------------------------------------------
// KAN1 (bf16 MFMA): expanded-A GEMM, K = 256 feat * 16 (silu, 8 bases, 7 pad)
// BM=128, BN=128 (full), K-step = 8 feat = 128.  grid 256, block 512 (8 waves)
// wave (wr,wc) = (wid>>2, wid&3) owns 64x32 output tile.
// ---------------------------------------------------------------------------
__global__ __launch_bounds__(512) void kan1_mfma(
        const float* __restrict__ H,            // 32768 x 256 f32
        const unsigned short* __restrict__ Bp,  // 128 x 4096 bf16 (padded)
        unsigned short* __restrict__ H2) {      // 32768 x 128 bf16
    __shared__ char lds[65536];   // phi 32 KB | Bs 32 KB
    char* smP = lds;
    char* smB = lds + 32768;
    const int r0 = blockIdx.x * 128;
    const int t = threadIdx.x;
    const int lane = t & 63, wid = t >> 6;
    const int wr = wid >> 2, wc = wid & 3;
    const int fr = lane & 15;
    const int fkb = (lane >> 4) * 8;

    f32x4 zero4 = {0.f, 0.f, 0.f, 0.f};
    f32x4 acc[4][2];
#pragma unroll
    for (int mt = 0; mt < 4; ++mt)
#pragma unroll
        for (int nt = 0; nt < 2; ++nt) acc[mt][nt] = zero4;

    for (int jb = 0; jb < 256; jb += 8) {
        // phi staging: 1024 (row, feature) expansions, 2 per thread
#pragma unroll
        for (int q = 0; q < 2; ++q) {
            const int p = t + q * 512;
            const int row = p & 127;
            const int f = p >> 7;                  // local feature 0..7
            const float x = H[(size_t)(r0 + row) * 256 + jb + f];
            float bs[8];
            bspline8(x, bs);
            const uint32_t w0 = pack2(silu_f(x), bs[0]);
            const uint32_t w1 = pack2(bs[1], bs[2]);
            const uint32_t w2 = pack2(bs[3], bs[4]);
            const uint32_t w3 = pack2(bs[5], bs[6]);
            const uint32_t w4 = pack2(bs[7], 0.f);
            const uint32_t swz = (uint32_t)(row & 15) << 4;
            const uint32_t base = (uint32_t)row * 256u + (uint32_t)f * 32u;
            *reinterpret_cast<int4*>(smP + (base ^ swz)) =
                make_int4((int)w0, (int)w1, (int)w2, (int)w3);
            *reinterpret_cast<int4*>(smP + ((base + 16u) ^ swz)) =
                make_int4((int)w4, 0, 0, 0);
        }
        // B staging: 32 KB, 4 x 16B per thread (coalesced 256B per 16 lanes)
#pragma unroll
        for (int q = 0; q < 4; ++q) {
            const int idx = q * 512 + t;           // 0..2047
            const int n = idx >> 4;                // 0..127
            const int kc = (idx & 15) * 8;         // local k, 0..120
            const int4 w = *reinterpret_cast<const int4*>(
                &Bp[(size_t)n * 4096 + jb * 16 + kc]);
            uint32_t off = ((uint32_t)n * 256u + (uint32_t)kc * 2u) ^
                           ((uint32_t)(n & 15) << 4);
            *reinterpret_cast<int4*>(smB + off) = w;
        }
        __syncthreads();
#pragma unroll
        for (int ks = 0; ks < 4; ++ks) {
            const int kb = ks * 32 + fkb;
            bf16x8 a[4], b[2];
#pragma unroll
            for (int mt = 0; mt < 4; ++mt) {
                uint32_t row = (uint32_t)(wr * 64 + mt * 16 + fr);
                uint32_t off = (row * 256u + (uint32_t)kb * 2u) ^ ((row & 15u) << 4);
                a[mt] = *reinterpret_cast<const bf16x8*>(smP + off);
            }
#pragma unroll
            for (int nt = 0; nt < 2; ++nt) {
                uint32_t row = (uint32_t)(wc * 32 + nt * 16 + fr);
                uint32_t off = (row * 256u + (uint32_t)kb * 2u) ^ ((row & 15u) << 4);
                b[nt] = *reinterpret_cast<const bf16x8*>(smB + off);
            }
#pragma unroll
            for (int mt = 0; mt < 4; ++mt)
#pragma unroll
                for (int nt = 0; nt < 2; ++nt)
                    acc[mt][nt] = __builtin_amdgcn_mfma_f32_16x16x32_bf16(
                        a[mt], b[nt], acc[mt][nt], 0, 0, 0);
        }
        __syncthreads();
    }
#pragma unroll
    for (int mt = 0; mt < 4; ++mt)
#pragma unroll
        for (int nt = 0; nt < 2; ++nt)
#pragma unroll
            for (int j = 0; j < 4; ++j) {
                const int row = r0 + wr * 64 + mt * 16 + (lane >> 4) * 4 + j;
                const int col = wc * 32 + nt * 16 + fr;
                H2[(size_t)row * 128 + col] = f2bf(acc[mt][nt][j]);
            }
}

// ---------------------------------------------------------------------------
// KAN2 + sigmoid: one wave per output row
// ---------------------------------------------------------------------------
__global__ __launch_bounds__(256) void kan2_kernel(
        const unsigned short* __restrict__ H2, const float* __restrict__ w2b,
        const float* __restrict__ w2s, float* __restrict__ out) {
    const int wave = threadIdx.x >> 6;
    const int lane = threadIdx.x & 63;
    const int row = blockIdx.x * 4 + wave;
    float sum = 0.f;
#pragma unroll
    for (int half = 0; half < 2; ++half) {
        const int j = lane + half * 64;
        const float x = bf2f(H2[(size_t)row * 128 + j]);
        float bs[8];
        bspline8(x, bs);
        float s = silu_f(x) * w2b[j];
#pragma unroll
        for (int v = 0; v < 8; ++v) s += bs[v] * w2s[j * 8 + v];
        sum += s;
    }
#pragma unroll
    for (int off = 32; off > 0; off >>= 1) sum += __shfl_down(sum, off, 64);
    if (lane == 0) out[row] = 1.0f / (1.0f + __expf(-sum));
}

// ---------------------------------------------------------------------------
extern "C" void kernel_launch(void* const* d_in, const int* in_sizes, int n_in,
                              void* d_out, int out_size, void* d_ws, size_t ws_size,
                              hipStream_t stream) {
    const float* stm  = (const float*)d_in[0];
    const float* nstm = (const float*)d_in[1];
    const float* ft_w = (const float*)d_in[2];
    const float* ft_b = (const float*)d_in[3];
    const float* k1bw = (const float*)d_in[4];
    const float* k1sw = (const float*)d_in[5];
    const float* k2bw = (const float*)d_in[6];
    const float* k2sw = (const float*)d_in[7];
    float* out = (float*)d_out;

    char* ws = (char*)d_ws;
    float* H = (float*)ws;                                            // 33,554,432 B
    unsigned short* H2 = (unsigned short*)(ws + 33554432);            //  8,388,608 B
    unsigned short* Wb = (unsigned short*)(ws + 33554432 + 8388608);  //    196,608 B
    unsigned short* Bp = (unsigned short*)(ws + 33554432 + 8388608 + 196608); // 1,048,576 B

    prep_ftw<<<384, 256, 0, stream>>>(ft_w, Wb);
    prep_bp<<<2048, 256, 0, stream>>>(k1bw, k1sw, Bp);
    ft_mfma<<<dim3(256, 2), 256, 0, stream>>>(stm, nstm, Wb, ft_b, H);
    kan1_mfma<<<256, 512, 0, stream>>>(H, Bp, H2);
    kan2_kernel<<<8192, 256, 0, stream>>>(H2, k2bw, k2sw, out);
}